// Round 2
// baseline (307.422 us; speedup 1.0000x reference)
//
#include <hip/hip_runtime.h>

// DynamicUpsamplingFilter: out[b,c,h,w] = sum_{dy,dx} f[b,3*dy+dx,h,w] * x[b,c,h+dy-1,w+dx-1]
// x: [B,128,180,320] f32, filters: [B,9,180,320] f32, out: [B,128,180,320] f32.
//
// R2 design: block = one (b,h). Filters row staged to LDS once then register-
// cached per thread (9 f4 at fixed w4) -> filter L2 traffic 1.06 GB -> 8 MB.
// x staged per 8-channel chunk into padded LDS rows (4-float zero guard each
// side, stride 328 floats) -> halo reads are aligned ds_read_b128, no scalar
// global loads. Per output-float4: 3 global loads + 1 store (was 19 vmem).

#define CC 128
#define HH 180
#define WW 320
#define W4 80
#define NF 9
#define CHUNK 8
#define NCHUNK (CC / CHUNK)   // 16
#define RS 328                 // LDS x row stride (floats): 4 pad + 320 + 4 pad
#define XS_CH (3 * RS)         // 984 floats per channel (3 rows)
#define NT 320                 // threads per block (5 waves)

__global__ __launch_bounds__(NT, 4) void duf_kernel(
    const float* __restrict__ x,
    const float* __restrict__ f,
    float* __restrict__ out)
{
    __shared__ float fs[NF * WW];          // 11520 B
    __shared__ float xs[CHUNK * 3 * RS];   // 31488 B

    const int t = threadIdx.x;
    const int h = blockIdx.x % HH;
    const int b = blockIdx.x / HH;

    // ---- stage filter row: 9 planes x 320 floats = 720 float4
    for (int idx = t; idx < NF * W4; idx += NT) {
        int i  = idx / W4;
        int w4 = idx % W4;
        ((float4*)fs)[idx] =
            ((const float4*)f)[((size_t)(b * NF + i) * HH + h) * W4 + w4];
    }
    // ---- zero the guard pads (left dwords [0..3], right [324..327], 24 rows)
    for (int idx = t; idx < CHUNK * 3 * 2; idx += NT) {
        int r = idx >> 1;
        int side = idx & 1;
        ((float4*)&xs[r * RS + side * (RS - 4)])[0] =
            make_float4(0.f, 0.f, 0.f, 0.f);
    }

    const int w4    = t % W4;   // 0..79  (lanes consecutive in w4 -> coalesced)
    const int cslot = t / W4;   // 0..3   (each handles 2 channels per chunk)

    float4 fr[NF];              // register-cached filters, fixed w4

    for (int chunk = 0; chunk < NCHUNK; ++chunk) {
        if (chunk) __syncthreads();   // WAR: prev compute done before overwrite

        // ---- stage x: 8 ch x 3 rows x 80 f4 = 1920 f4, coalesced
        const int c0 = chunk * CHUNK;
#pragma unroll
        for (int it = 0; it < 6; ++it) {
            int idx = it * NT + t;            // < 1920
            int lw4 = idx % W4;
            int rr  = (idx / W4) % 3;
            int ch  = idx / 240;
            int hh  = h - 1 + rr;
            float4 v = make_float4(0.f, 0.f, 0.f, 0.f);
            if (hh >= 0 && hh < HH)
                v = ((const float4*)x)[((size_t)(b * CC + c0 + ch) * HH + hh) * W4 + lw4];
            ((float4*)&xs[ch * XS_CH + rr * RS + 4])[lw4] = v;
        }
        __syncthreads();                      // RAW: x chunk visible

        if (chunk == 0) {
#pragma unroll
            for (int i = 0; i < NF; ++i)
                fr[i] = ((const float4*)&fs[i * WW])[w4];
        }

        // ---- compute 2 channels at fixed w4
#pragma unroll
        for (int j = 0; j < 2; ++j) {
            int ch = cslot * 2 + j;
            float4 acc = make_float4(0.f, 0.f, 0.f, 0.f);
#pragma unroll
            for (int dy = 0; dy < 3; ++dy) {
                const float4* rp = (const float4*)&xs[ch * XS_CH + dy * RS];
                float4 A = rp[w4];        // .w = x[4w-1]
                float4 B = rp[w4 + 1];    // x[4w .. 4w+3]
                float4 C = rp[w4 + 2];    // .x = x[4w+4]
                float4 f0 = fr[3 * dy + 0];
                float4 f1 = fr[3 * dy + 1];
                float4 f2 = fr[3 * dy + 2];
                acc.x = fmaf(f0.x, A.w, fmaf(f1.x, B.x, fmaf(f2.x, B.y, acc.x)));
                acc.y = fmaf(f0.y, B.x, fmaf(f1.y, B.y, fmaf(f2.y, B.z, acc.y)));
                acc.z = fmaf(f0.z, B.y, fmaf(f1.z, B.z, fmaf(f2.z, B.w, acc.z)));
                acc.w = fmaf(f0.w, B.z, fmaf(f1.w, B.w, fmaf(f2.w, C.x, acc.w)));
            }
            ((float4*)out)[((size_t)(b * CC + c0 + ch) * HH + h) * W4 + w4] = acc;
        }
    }
}

extern "C" void kernel_launch(void* const* d_in, const int* in_sizes, int n_in,
                              void* d_out, int out_size, void* d_ws, size_t ws_size,
                              hipStream_t stream) {
    const float* x = (const float*)d_in[0];
    const float* f = (const float*)d_in[1];
    float* out = (float*)d_out;

    int B = in_sizes[0] / (CC * HH * WW);   // 4
    int blocks = B * HH;                    // 720

    duf_kernel<<<blocks, NT, 0, stream>>>(x, f, out);
}

// Round 3
// 240.483 us; speedup vs baseline: 1.2784x; 1.2784x over previous
//
#include <hip/hip_runtime.h>

// DynamicUpsamplingFilter: out[b,c,h,w] = sum_{dy,dx} f[b,3*dy+dx,h,w] * x[b,c,h+dy-1,w+dx-1]
// x: [4,128,180,320] f32, filters: [4,9,180,320] f32, out: [4,128,180,320] f32.
//
// R3: pure-register design. Thread = (b, h-pair, w4, 8-channel group).
// 18 filter float4s register-cached once (reused over 8 channels); x rows
// streamed as aligned A/B/C float4s (clamp + cndmask edges, no scalar halo
// loads); each x row feeds both output rows of the h-pair.
// vmem instructions per output-float4: (18 + 8*(12+2))/16 ~= 8.1 (R1 was 20).

#define CC 128
#define HH 180
#define W4 80
#define NF 9
#define CPT 8
#define H2 (HH / 2)    // 90
#define NCG (CC / CPT) // 16

__device__ __forceinline__ void fma_row(float4& acc, float4 f0, float4 f1,
                                        float4 f2, float4 A, float4 B, float4 C) {
    acc.x = fmaf(f0.x, A.w, fmaf(f1.x, B.x, fmaf(f2.x, B.y, acc.x)));
    acc.y = fmaf(f0.y, B.x, fmaf(f1.y, B.y, fmaf(f2.y, B.z, acc.y)));
    acc.z = fmaf(f0.z, B.y, fmaf(f1.z, B.z, fmaf(f2.z, B.w, acc.z)));
    acc.w = fmaf(f0.w, B.z, fmaf(f1.w, B.w, fmaf(f2.w, C.x, acc.w)));
}

__global__ __launch_bounds__(256) void duf_kernel(
    const float* __restrict__ x,
    const float* __restrict__ f,
    float* __restrict__ out)
{
    int n = blockIdx.x * 256 + threadIdx.x;
    // n = ((b*H2 + h2)*NCG + cg)*W4 + w4  -> lanes consecutive in w4
    int w4 = n % W4;
    int t  = n / W4;
    int cg = t % NCG;
    t /= NCG;
    int h2 = t % H2;
    int b  = t / H2;
    int h  = h2 * 2;

    const float4* x4 = (const float4*)x;
    const float4* f4 = (const float4*)f;
    float4* o4 = (float4*)out;

    // ---- register-cache the 9 taps for both output rows (18 float4)
    float4 fr0[NF], fr1[NF];
    size_t fbase = ((size_t)(b * NF) * HH + h) * W4 + w4;
#pragma unroll
    for (int i = 0; i < NF; ++i) {
        fr0[i] = f4[fbase + (size_t)i * HH * W4];
        fr1[i] = f4[fbase + (size_t)i * HH * W4 + W4];
    }

    const int wl = (w4 > 0) ? w4 - 1 : 0;          // clamped left f4
    const int wr = (w4 < W4 - 1) ? w4 + 1 : w4;    // clamped right f4
    const bool at_l = (w4 == 0);
    const bool at_r = (w4 == W4 - 1);

    const int c0 = cg * CPT;
    for (int cc = 0; cc < CPT; ++cc) {
        const size_t xb = (size_t)(b * CC + c0 + cc) * HH * W4;
        float4 a0 = make_float4(0.f, 0.f, 0.f, 0.f);
        float4 a1 = make_float4(0.f, 0.f, 0.f, 0.f);
#pragma unroll
        for (int r = 0; r < 4; ++r) {              // x rows h-1 .. h+2
            int hr = h - 1 + r;
            float4 A = make_float4(0.f, 0.f, 0.f, 0.f);
            float4 B = A, C = A;
            if (hr >= 0 && hr < HH) {              // wave-uniform branch
                size_t rb = xb + (size_t)hr * W4;
                A = x4[rb + wl];
                B = x4[rb + w4];
                C = x4[rb + wr];
                if (at_l) A.w = 0.f;
                if (at_r) C.x = 0.f;
            }
            if (r < 3) fma_row(a0, fr0[3*r  ], fr0[3*r+1], fr0[3*r+2], A, B, C);
            if (r > 0) fma_row(a1, fr1[3*r-3], fr1[3*r-2], fr1[3*r-1], A, B, C);
        }
        size_t ob = ((size_t)(b * CC + c0 + cc) * HH + h) * W4 + w4;
        o4[ob]      = a0;
        o4[ob + W4] = a1;
    }
}

extern "C" void kernel_launch(void* const* d_in, const int* in_sizes, int n_in,
                              void* d_out, int out_size, void* d_ws, size_t ws_size,
                              hipStream_t stream) {
    const float* x = (const float*)d_in[0];
    const float* f = (const float*)d_in[1];
    float* out = (float*)d_out;

    int B = in_sizes[0] / (CC * HH * W4 * 4);     // 4
    int total = B * H2 * NCG * W4;                // 460800 threads
    duf_kernel<<<total / 256, 256, 0, stream>>>(x, f, out);
}